// Round 5
// baseline (222.106 us; speedup 1.0000x reference)
//
#include <hip/hip_runtime.h>

#define BS 16
#define VL 1024
#define QL 64
#define DM 1024
#define MM (BS*VL)

typedef __attribute__((ext_vector_type(8))) short bf16x8;
typedef __attribute__((ext_vector_type(4))) float f32x4;

__device__ __forceinline__ unsigned short f2bf_rne(float f) {
  unsigned int u = __float_as_uint(f);
  u += 0x7fffu + ((u >> 16) & 1u);
  return (unsigned short)(u >> 16);
}
__device__ __forceinline__ void gl16(const void* g, void* l) {
  __builtin_amdgcn_global_load_lds(
      (const __attribute__((address_space(1))) unsigned int*)g,
      (__attribute__((address_space(3))) unsigned int*)l, 16, 0, 0);
}

// ---- k_sent: grid (b=16, dc=8). Redundant per-block alpha (cheap), then
// softmax + weighted pool of the dc-chunk; psq[b*8+dc] = partial ||sentence||^2.
__global__ __launch_bounds__(256) void k_sent(
    const float* __restrict__ query, const float* __restrict__ qmask,
    const float* __restrict__ pool_w, float* __restrict__ sentence,
    float* __restrict__ psq)
{
  int b = blockIdx.x, dc = blockIdx.y, t = threadIdx.x;
  __shared__ float al[QL];
  __shared__ float red2[2][128];
  __shared__ float sqred[2];
  const float* qb = query + (size_t)b*QL*DM;
  {
    int q = t >> 2, part = t & 3;                  // 4 threads per query row
    const float4* rp = (const float4*)(qb + q*DM + part*256);
    const float4* pp = (const float4*)(pool_w + part*256);
    float s = 0.f;
    for (int i = 0; i < 64; ++i) {
      float4 a = rp[i], w = pp[i];
      s += a.x*w.x + a.y*w.y + a.z*w.z + a.w*w.w;
    }
    s += __shfl_xor(s, 1);
    s += __shfl_xor(s, 2);
    if (part == 0) al[q] = s;
  }
  __syncthreads();
  if (t < 64) {                                    // softmax over q (one wave)
    float a = al[t] + (1.f - qmask[b*QL + t]) * (-1e30f);
    float m = a;
    #pragma unroll
    for (int off = 32; off; off >>= 1) m = fmaxf(m, __shfl_xor(m, off));
    float e = expf(a - m);
    float ssum = e;
    #pragma unroll
    for (int off = 32; off; off >>= 1) ssum += __shfl_xor(ssum, off);
    al[t] = e / ssum;
  }
  __syncthreads();
  int col = t & 127, half = t >> 7;
  const float* qp = qb + dc*128 + col;
  float acc = 0.f;
  for (int q = half*32; q < half*32 + 32; ++q)
    acc += al[q] * qp[(size_t)q*DM];
  red2[half][col] = acc;
  __syncthreads();
  if (t < 128) {
    float s = red2[0][t] + red2[1][t];
    sentence[(size_t)b*DM + dc*128 + t] = s;
    float sq = s*s;
    #pragma unroll
    for (int off = 32; off; off >>= 1) sq += __shfl_xor(sq, off);
    if ((t & 63) == 0) sqred[t >> 6] = sq;
  }
  __syncthreads();
  if (t == 0) psq[b*8 + dc] = sqred[0] + sqred[1];
}

// ---- GEMVs: partial[kchunk(32)][18][1024]; 256 blocks, no atomics -------------
// rows 0..15: sentence[b]@W2 ; 16: sim_w@W1 ; 17: (cor_v*cor_q)@W3
__global__ __launch_bounds__(256) void k_gemvs(
    const float* __restrict__ mixer_w, const float* __restrict__ sentence,
    const float* __restrict__ sim_w, const float* __restrict__ cor_v_w,
    const float* __restrict__ cor_q_w, float* __restrict__ partial)
{
  int d0 = blockIdx.x * 32;
  int n0 = blockIdx.y * 128;
  int t = threadIdx.x;
  int col = t & 127, kh = t >> 7;
  __shared__ float vec[18][32];
  __shared__ float red[2][18][128];
  for (int i = t; i < 18*32; i += 256) {
    int b = i >> 5, k = i & 31;
    float val;
    if (b < 16)       val = sentence[(size_t)b*DM + d0 + k];
    else if (b == 16) val = sim_w[d0 + k];
    else              val = cor_v_w[d0 + k] * cor_q_w[0];
    vec[b][k] = val;
  }
  __syncthreads();
  float acc[18];
  #pragma unroll
  for (int j = 0; j < 18; ++j) acc[j] = 0.f;
  const float* Wb = mixer_w + (size_t)(d0 + kh*16)*DM + n0 + col;
  #pragma unroll 1
  for (int k = 0; k < 16; ++k) {
    const float* wr = Wb + (size_t)k*DM;
    float w1 = wr[(size_t)1*DM*DM];
    float w2 = wr[(size_t)2*DM*DM];
    float w3 = wr[(size_t)3*DM*DM];
    int kk = kh*16 + k;
    #pragma unroll
    for (int b = 0; b < 16; ++b) acc[b] += vec[b][kk] * w2;
    acc[16] += vec[16][kk] * w1;
    acc[17] += vec[17][kk] * w3;
  }
  #pragma unroll
  for (int j = 0; j < 18; ++j) red[kh][j][col] = acc[j];
  __syncthreads();
  #pragma unroll
  for (int r = 0; r < 9; ++r) {
    int idx = t + 256*r;
    int j = idx >> 7, c2 = idx & 127;
    partial[((size_t)blockIdx.x*18 + j)*1024 + n0 + c2] = red[0][j][c2] + red[1][j][c2];
  }
}

// ---- fused: blocks <4096: video -> bf16 A + sim ; >=4096: W_v -> B^T -----------
__global__ __launch_bounds__(256) void k_conv(
    const float* __restrict__ video, const float* __restrict__ sentence,
    const float* __restrict__ psq, const float* __restrict__ vmask,
    const float* __restrict__ Wv,
    unsigned short* __restrict__ Ahi, unsigned short* __restrict__ Bhi,
    float* __restrict__ simv)
{
  __shared__ float tile[64][65];
  int t = threadIdx.x;
  if (blockIdx.x < 4096) {
    int wave = t >> 6, lane = t & 63;
    int row = blockIdx.x * 4 + wave;
    int b = row >> 10;
    const float4* vp = (const float4*)(video + (size_t)row*DM);
    const float4* sp = (const float4*)(sentence + (size_t)b*DM);
    float dot = 0.f, sq = 0.f;
    #pragma unroll
    for (int i = 0; i < 4; ++i) {
      float4 v = vp[lane + 64*i];
      float4 s = sp[lane + 64*i];
      dot += v.x*s.x + v.y*s.y + v.z*s.z + v.w*s.w;
      sq  += v.x*v.x + v.y*v.y + v.z*v.z + v.w*v.w;
      ushort4 h;
      h.x = f2bf_rne(v.x); h.y = f2bf_rne(v.y);
      h.z = f2bf_rne(v.z); h.w = f2bf_rne(v.w);
      *(ushort4*)(Ahi + (size_t)row*DM + (lane + 64*i)*4) = h;
    }
    #pragma unroll
    for (int off = 32; off; off >>= 1) {
      dot += __shfl_xor(dot, off);
      sq  += __shfl_xor(sq,  off);
    }
    if (lane == 0) {
      float ss = 0.f;
      #pragma unroll
      for (int i = 0; i < 8; ++i) ss += psq[b*8 + i];
      float snv = fmaxf(sqrtf(ss), 1e-8f);
      float vn  = fmaxf(sqrtf(sq), 1e-8f);
      simv[row] = dot / (vn * snv) + logf(vmask[row] + 1e-45f);
    }
  } else {
    int bb = blockIdx.x - 4096;
    int bk = (bb & 15) * 64;
    int bn = (bb >> 4) * 64;
    int kr = t >> 2, nc = (t & 3) * 16;
    const float4* src = (const float4*)(Wv + (size_t)(bk + kr)*DM + bn + nc);
    #pragma unroll
    for (int i = 0; i < 4; ++i) {
      float4 v = src[i];
      tile[kr][nc + i*4 + 0] = v.x;
      tile[kr][nc + i*4 + 1] = v.y;
      tile[kr][nc + i*4 + 2] = v.z;
      tile[kr][nc + i*4 + 3] = v.w;
    }
    __syncthreads();
    int n = t >> 2, kc = (t & 3) * 16;
    #pragma unroll
    for (int i = 0; i < 16; i += 4) {
      ushort4 h;
      h.x = f2bf_rne(tile[kc+i+0][n]);
      h.y = f2bf_rne(tile[kc+i+1][n]);
      h.z = f2bf_rne(tile[kc+i+2][n]);
      h.w = f2bf_rne(tile[kc+i+3][n]);
      *(ushort4*)(Bhi + (size_t)(bn+n)*DM + bk + kc + i) = h;
    }
  }
}

// ---- main GEMM (r3-proven 2-phase structure) + in-prologue column reduction ----
// out = relu(video@W_v + sim*u_s + u_c + base + bias)
// 128x128 tile, BK=64, 2-phase LDS dbuf, XOR-swizzled LDS image (src-side),
// epilogue constants (u_s/u_c/base reduced from `partial`) computed in prologue
// overlapped with the first STAGE's load latency.
__global__ __launch_bounds__(256) void k_gemm(
    const unsigned short* __restrict__ Ahi, const unsigned short* __restrict__ Bhi,
    const float* __restrict__ simv, const float* __restrict__ partial,
    const float* __restrict__ mixer_b, float* __restrict__ out)
{
  __shared__ __align__(16) unsigned short At[2][128][64];   // 32 KB
  __shared__ __align__(16) unsigned short Bt[2][128][64];   // 32 KB
  __shared__ float bL[128], uL[128], cL[128];               // 1.5 KB

  int bid = blockIdx.x;
  // bijective XCD swizzle (nwg=1024, 1024%8==0)
  int swz = (bid & 7) * 128 + (bid >> 3);
  int bm = swz >> 3;          // 0..127
  int bn = swz & 7;           // 0..7
  int batch = bm >> 3;        // 128 rows per bm, 1024 per batch

  int t = threadIdx.x;
  int wave = t >> 6, lane = t & 63;
  int wm = (wave >> 1) * 64, wn = (wave & 1) * 64;
  int lr = lane & 15, g = lane >> 4;
  int rx = 8 * (lr & 7);      // read-side XOR (elems; rows mod 8)

  f32x4 acc[4][4];
  #pragma unroll
  for (int i = 0; i < 4; ++i)
    #pragma unroll
    for (int j = 0; j < 4; ++j) acc[i][j] = (f32x4){0.f, 0.f, 0.f, 0.f};

  // staging: image[row][col'] with col' = col ^ (8*(row&7)); LDS write linear,
  // gather from source col = 8*((chunk j) ^ (row&7)).
  int srow = t >> 3;                       // 0..31 (+32q)
  int scol = 8 * ((t & 7) ^ (srow & 7));   // row&7 invariant under +32q
  const unsigned short* Ap = Ahi + (size_t)(bm*128 + srow)*DM + scol;
  const unsigned short* Bp = Bhi + (size_t)(bn*128 + srow)*DM + scol;
  char* ldsA = (char*)&At[0][0][0] + wave*1024;
  char* ldsB = (char*)&Bt[0][0][0] + wave*1024;

  #define STAGE(kt, buf) do {                                         \
    const unsigned short* _a = Ap + (kt)*64;                          \
    const unsigned short* _b = Bp + (kt)*64;                          \
    _Pragma("unroll")                                                 \
    for (int q = 0; q < 4; ++q) {                                     \
      gl16(_a + (size_t)q*32*DM, ldsA + (buf)*16384 + q*4096);        \
      gl16(_b + (size_t)q*32*DM, ldsB + (buf)*16384 + q*4096);        \
    }                                                                 \
  } while (0)

  STAGE(0, 0);

  // column reduction for this block's 128 output cols (overlaps STAGE latency):
  // bL = basev[batch], uL = u_s, cL = u_c   (summed over 32 k-chunks)
  {
    int nbase = bn * 128;
    if (t < 128) {
      float s = 0.f;
      #pragma unroll 4
      for (int kc = 0; kc < 32; ++kc)
        s += partial[((size_t)kc*18 + batch)*1024 + nbase + t];
      bL[t] = s;
    } else {
      int c = t - 128;
      float s16 = 0.f, s17 = 0.f;
      #pragma unroll 4
      for (int kc = 0; kc < 32; ++kc) {
        s16 += partial[((size_t)kc*18 + 16)*1024 + nbase + c];
        s17 += partial[((size_t)kc*18 + 17)*1024 + nbase + c];
      }
      uL[c] = s16; cL[c] = s17;
    }
  }
  __syncthreads();

  #pragma unroll 1
  for (int kt = 0; kt < 16; ++kt) {
    int buf = kt & 1;
    if (kt < 15) STAGE(kt + 1, buf ^ 1);   // issue loads first: overlap w/ compute
    const unsigned short* Ab = &At[buf][0][0];
    const unsigned short* Bb = &Bt[buf][0][0];
    #pragma unroll
    for (int s = 0; s < 2; ++s) {
      int cb = (s*32 + 8*g) ^ rx;          // swizzled column of this frag
      bf16x8 af[4], bfr[4];
      #pragma unroll
      for (int mi = 0; mi < 4; ++mi)
        af[mi] = *(const bf16x8*)(Ab + (wm + mi*16 + lr)*64 + cb);
      #pragma unroll
      for (int nj = 0; nj < 4; ++nj)
        bfr[nj] = *(const bf16x8*)(Bb + (wn + nj*16 + lr)*64 + cb);
      #pragma unroll
      for (int mi = 0; mi < 4; ++mi)
        #pragma unroll
        for (int nj = 0; nj < 4; ++nj)
          acc[mi][nj] = __builtin_amdgcn_mfma_f32_16x16x32_bf16(
              af[mi], bfr[nj], acc[mi][nj], 0, 0, 0);
    }
    __syncthreads();   // drains vmcnt: next buf staged; cur buf free for reuse
  }

  // epilogue: C/D layout col=lane&15, row=(lane>>4)*4+reg  [m89]
  int orow0 = bm*128 + wm;
  int ocol0 = bn*128 + wn;
  float usv[4], cv[4];
  #pragma unroll
  for (int nj = 0; nj < 4; ++nj) {
    int lc = wn + nj*16 + lr;              // 0..127 within block's cols
    usv[nj] = uL[lc];
    cv[nj]  = bL[lc] + cL[lc] + mixer_b[ocol0 + nj*16 + lr];
  }
  int rbase = g * 4;
  #pragma unroll
  for (int mi = 0; mi < 4; ++mi) {
    #pragma unroll
    for (int r = 0; r < 4; ++r) {
      int row = orow0 + mi*16 + rbase + r;
      float sim = simv[row];
      #pragma unroll
      for (int nj = 0; nj < 4; ++nj) {
        float v = acc[mi][nj][r] + sim*usv[nj] + cv[nj];
        out[(size_t)row*DM + ocol0 + nj*16 + lr] = fmaxf(v, 0.f);
      }
    }
  }
  #undef STAGE
}

extern "C" void kernel_launch(void* const* d_in, const int* in_sizes, int n_in,
                              void* d_out, int out_size, void* d_ws, size_t ws_size,
                              hipStream_t stream) {
  const float* video   = (const float*)d_in[0];
  const float* query   = (const float*)d_in[1];
  const float* vmask   = (const float*)d_in[2];
  const float* qmask   = (const float*)d_in[3];
  const float* sim_w   = (const float*)d_in[4];
  const float* cor_v_w = (const float*)d_in[5];
  const float* cor_q_w = (const float*)d_in[6];
  const float* pool_w  = (const float*)d_in[7];
  const float* mixer_w = (const float*)d_in[8];
  const float* mixer_b = (const float*)d_in[9];
  float* out = (float*)d_out;

  float* fws      = (float*)d_ws;
  float* sentence = fws;                    // 16384
  float* psq      = sentence + 16384;       // 128
  float* simv     = psq + 128;              // 16384
  float* partial  = simv + 16384;           // 32*18*1024 = 589824
  unsigned short* Ahi = (unsigned short*)(partial + 589824);  // 16M elems (32MB)
  unsigned short* Bhi = Ahi + (size_t)MM*DM;                  // 1M elems (2MB)

  k_sent<<<dim3(16, 8), dim3(256), 0, stream>>>(query, qmask, pool_w,
                                                sentence, psq);
  k_gemvs<<<dim3(32, 8), dim3(256), 0, stream>>>(mixer_w, sentence, sim_w,
                                                 cor_v_w, cor_q_w, partial);
  k_conv<<<dim3(4352), dim3(256), 0, stream>>>(video, sentence, psq, vmask,
                                               mixer_w, Ahi, Bhi, simv);
  k_gemm<<<dim3(1024), dim3(256), 0, stream>>>(Ahi, Bhi, simv, partial,
                                               mixer_b, out);
}

// Round 6
// 214.900 us; speedup vs baseline: 1.0335x; 1.0335x over previous
//
#include <hip/hip_runtime.h>

#define BS 16
#define VL 1024
#define QL 64
#define DM 1024
#define MM (BS*VL)

typedef __attribute__((ext_vector_type(8))) short bf16x8;
typedef __attribute__((ext_vector_type(4))) float f32x4;

__device__ __forceinline__ unsigned short f2bf_rne(float f) {
  unsigned int u = __float_as_uint(f);
  u += 0x7fffu + ((u >> 16) & 1u);
  return (unsigned short)(u >> 16);
}
__device__ __forceinline__ void gl16(const void* g, void* l) {
  __builtin_amdgcn_global_load_lds(
      (const __attribute__((address_space(1))) unsigned int*)g,
      (__attribute__((address_space(3))) unsigned int*)l, 16, 0, 0);
}

// ---- k_sent: grid (b=16, dc=8). Redundant per-block alpha (cheap), then
// softmax + weighted pool of the dc-chunk; psq[b*8+dc] = partial ||sentence||^2.
__global__ __launch_bounds__(256) void k_sent(
    const float* __restrict__ query, const float* __restrict__ qmask,
    const float* __restrict__ pool_w, float* __restrict__ sentence,
    float* __restrict__ psq)
{
  int b = blockIdx.x, dc = blockIdx.y, t = threadIdx.x;
  __shared__ float al[QL];
  __shared__ float red2[2][128];
  __shared__ float sqred[2];
  const float* qb = query + (size_t)b*QL*DM;
  {
    int q = t >> 2, part = t & 3;                  // 4 threads per query row
    const float4* rp = (const float4*)(qb + q*DM + part*256);
    const float4* pp = (const float4*)(pool_w + part*256);
    float s = 0.f;
    for (int i = 0; i < 64; ++i) {
      float4 a = rp[i], w = pp[i];
      s += a.x*w.x + a.y*w.y + a.z*w.z + a.w*w.w;
    }
    s += __shfl_xor(s, 1);
    s += __shfl_xor(s, 2);
    if (part == 0) al[q] = s;
  }
  __syncthreads();
  if (t < 64) {                                    // softmax over q (one wave)
    float a = al[t] + (1.f - qmask[b*QL + t]) * (-1e30f);
    float m = a;
    #pragma unroll
    for (int off = 32; off; off >>= 1) m = fmaxf(m, __shfl_xor(m, off));
    float e = expf(a - m);
    float ssum = e;
    #pragma unroll
    for (int off = 32; off; off >>= 1) ssum += __shfl_xor(ssum, off);
    al[t] = e / ssum;
  }
  __syncthreads();
  int col = t & 127, half = t >> 7;
  const float* qp = qb + dc*128 + col;
  float acc = 0.f;
  for (int q = half*32; q < half*32 + 32; ++q)
    acc += al[q] * qp[(size_t)q*DM];
  red2[half][col] = acc;
  __syncthreads();
  if (t < 128) {
    float s = red2[0][t] + red2[1][t];
    sentence[(size_t)b*DM + dc*128 + t] = s;
    float sq = s*s;
    #pragma unroll
    for (int off = 32; off; off >>= 1) sq += __shfl_xor(sq, off);
    if ((t & 63) == 0) sqred[t >> 6] = sq;
  }
  __syncthreads();
  if (t == 0) psq[b*8 + dc] = sqred[0] + sqred[1];
}

// ---- GEMVs: partial[kchunk(32)][18][1024]; 256 blocks, no atomics -------------
// rows 0..15: sentence[b]@W2 ; 16: sim_w@W1 ; 17: (cor_v*cor_q)@W3
__global__ __launch_bounds__(256) void k_gemvs(
    const float* __restrict__ mixer_w, const float* __restrict__ sentence,
    const float* __restrict__ sim_w, const float* __restrict__ cor_v_w,
    const float* __restrict__ cor_q_w, float* __restrict__ partial)
{
  int d0 = blockIdx.x * 32;
  int n0 = blockIdx.y * 128;
  int t = threadIdx.x;
  int col = t & 127, kh = t >> 7;
  __shared__ float vec[18][32];
  __shared__ float red[2][18][128];
  for (int i = t; i < 18*32; i += 256) {
    int b = i >> 5, k = i & 31;
    float val;
    if (b < 16)       val = sentence[(size_t)b*DM + d0 + k];
    else if (b == 16) val = sim_w[d0 + k];
    else              val = cor_v_w[d0 + k] * cor_q_w[0];
    vec[b][k] = val;
  }
  __syncthreads();
  float acc[18];
  #pragma unroll
  for (int j = 0; j < 18; ++j) acc[j] = 0.f;
  const float* Wb = mixer_w + (size_t)(d0 + kh*16)*DM + n0 + col;
  #pragma unroll 1
  for (int k = 0; k < 16; ++k) {
    const float* wr = Wb + (size_t)k*DM;
    float w1 = wr[(size_t)1*DM*DM];
    float w2 = wr[(size_t)2*DM*DM];
    float w3 = wr[(size_t)3*DM*DM];
    int kk = kh*16 + k;
    #pragma unroll
    for (int b = 0; b < 16; ++b) acc[b] += vec[b][kk] * w2;
    acc[16] += vec[16][kk] * w1;
    acc[17] += vec[17][kk] * w3;
  }
  #pragma unroll
  for (int j = 0; j < 18; ++j) red[kh][j][col] = acc[j];
  __syncthreads();
  #pragma unroll
  for (int r = 0; r < 9; ++r) {
    int idx = t + 256*r;
    int j = idx >> 7, c2 = idx & 127;
    partial[((size_t)blockIdx.x*18 + j)*1024 + n0 + c2] = red[0][j][c2] + red[1][j][c2];
  }
}

// ---- reduce partial over 32 k-chunks -> basev / u_s / u_c ---------------------
__global__ __launch_bounds__(256) void k_reduce(
    const float* __restrict__ partial, float* __restrict__ basev,
    float* __restrict__ u_s, float* __restrict__ u_c)
{
  int idx = blockIdx.x * 256 + threadIdx.x;        // 0..18431
  int j = idx >> 10, col = idx & 1023;
  float s = 0.f;
  #pragma unroll 4
  for (int b = 0; b < 32; ++b) s += partial[((size_t)b*18 + j)*1024 + col];
  if (j < 16)       basev[(size_t)j*1024 + col] = s;
  else if (j == 16) u_s[col] = s;
  else              u_c[col] = s;
}

// ---- fused: blocks <4096: video -> bf16 A + sim ; >=4096: W_v -> B^T -----------
__global__ __launch_bounds__(256) void k_conv(
    const float* __restrict__ video, const float* __restrict__ sentence,
    const float* __restrict__ psq, const float* __restrict__ vmask,
    const float* __restrict__ Wv,
    unsigned short* __restrict__ Ahi, unsigned short* __restrict__ Bhi,
    float* __restrict__ simv)
{
  __shared__ float tile[64][65];
  int t = threadIdx.x;
  if (blockIdx.x < 4096) {
    int wave = t >> 6, lane = t & 63;
    int row = blockIdx.x * 4 + wave;
    int b = row >> 10;
    const float4* vp = (const float4*)(video + (size_t)row*DM);
    const float4* sp = (const float4*)(sentence + (size_t)b*DM);
    float dot = 0.f, sq = 0.f;
    #pragma unroll
    for (int i = 0; i < 4; ++i) {
      float4 v = vp[lane + 64*i];
      float4 s = sp[lane + 64*i];
      dot += v.x*s.x + v.y*s.y + v.z*s.z + v.w*s.w;
      sq  += v.x*v.x + v.y*v.y + v.z*v.z + v.w*v.w;
      ushort4 h;
      h.x = f2bf_rne(v.x); h.y = f2bf_rne(v.y);
      h.z = f2bf_rne(v.z); h.w = f2bf_rne(v.w);
      *(ushort4*)(Ahi + (size_t)row*DM + (lane + 64*i)*4) = h;
    }
    #pragma unroll
    for (int off = 32; off; off >>= 1) {
      dot += __shfl_xor(dot, off);
      sq  += __shfl_xor(sq,  off);
    }
    if (lane == 0) {
      float ss = 0.f;
      #pragma unroll
      for (int i = 0; i < 8; ++i) ss += psq[b*8 + i];
      float snv = fmaxf(sqrtf(ss), 1e-8f);
      float vn  = fmaxf(sqrtf(sq), 1e-8f);
      simv[row] = dot / (vn * snv) + logf(vmask[row] + 1e-45f);
    }
  } else {
    int bb = blockIdx.x - 4096;
    int bk = (bb & 15) * 64;
    int bn = (bb >> 4) * 64;
    int kr = t >> 2, nc = (t & 3) * 16;
    const float4* src = (const float4*)(Wv + (size_t)(bk + kr)*DM + bn + nc);
    #pragma unroll
    for (int i = 0; i < 4; ++i) {
      float4 v = src[i];
      tile[kr][nc + i*4 + 0] = v.x;
      tile[kr][nc + i*4 + 1] = v.y;
      tile[kr][nc + i*4 + 2] = v.z;
      tile[kr][nc + i*4 + 3] = v.w;
    }
    __syncthreads();
    int n = t >> 2, kc = (t & 3) * 16;
    #pragma unroll
    for (int i = 0; i < 16; i += 4) {
      ushort4 h;
      h.x = f2bf_rne(tile[kc+i+0][n]);
      h.y = f2bf_rne(tile[kc+i+1][n]);
      h.z = f2bf_rne(tile[kc+i+2][n]);
      h.w = f2bf_rne(tile[kc+i+3][n]);
      *(ushort4*)(Bhi + (size_t)(bn+n)*DM + bk + kc + i) = h;
    }
  }
}

// ---- main GEMM (r3-proven form, 49us measured): 128x128 tile, BK=64,
// 2-phase LDS double-buffer, XOR-swizzled LDS image (source-side pre-swizzle,
// linear gl_lds dest, XOR on ds_read) -> 0 bank conflicts.
// out = relu(video@W_v + sim*u_s + u_c + base + bias)
__global__ __launch_bounds__(256) void k_gemm(
    const unsigned short* __restrict__ Ahi, const unsigned short* __restrict__ Bhi,
    const float* __restrict__ simv, const float* __restrict__ u_s,
    const float* __restrict__ u_c, const float* __restrict__ basev,
    const float* __restrict__ mixer_b, float* __restrict__ out)
{
  __shared__ __align__(16) unsigned short At[2][128][64];   // 32 KB
  __shared__ __align__(16) unsigned short Bt[2][128][64];   // 32 KB

  int bid = blockIdx.x;
  // bijective XCD swizzle (nwg=1024, 1024%8==0)
  int swz = (bid & 7) * 128 + (bid >> 3);
  int bm = swz >> 3;          // 0..127
  int bn = swz & 7;           // 0..7

  int t = threadIdx.x;
  int wave = t >> 6, lane = t & 63;
  int wm = (wave >> 1) * 64, wn = (wave & 1) * 64;
  int lr = lane & 15, g = lane >> 4;
  int rx = 8 * (lr & 7);      // read-side XOR (elems; rows mod 8)

  f32x4 acc[4][4];
  #pragma unroll
  for (int i = 0; i < 4; ++i)
    #pragma unroll
    for (int j = 0; j < 4; ++j) acc[i][j] = (f32x4){0.f, 0.f, 0.f, 0.f};

  // staging: image[row][col'] with col' = col ^ (8*(row&7)); LDS write linear,
  // gather from source col = 8*((chunk j) ^ (row&7)).
  int srow = t >> 3;                       // 0..31 (+32q)
  int scol = 8 * ((t & 7) ^ (srow & 7));   // row&7 invariant under +32q
  const unsigned short* Ap = Ahi + (size_t)(bm*128 + srow)*DM + scol;
  const unsigned short* Bp = Bhi + (size_t)(bn*128 + srow)*DM + scol;
  char* ldsA = (char*)&At[0][0][0] + wave*1024;
  char* ldsB = (char*)&Bt[0][0][0] + wave*1024;

  #define STAGE(kt, buf) do {                                         \
    const unsigned short* _a = Ap + (kt)*64;                          \
    const unsigned short* _b = Bp + (kt)*64;                          \
    _Pragma("unroll")                                                 \
    for (int q = 0; q < 4; ++q) {                                     \
      gl16(_a + (size_t)q*32*DM, ldsA + (buf)*16384 + q*4096);        \
      gl16(_b + (size_t)q*32*DM, ldsB + (buf)*16384 + q*4096);        \
    }                                                                 \
  } while (0)

  STAGE(0, 0);
  __syncthreads();

  #pragma unroll 1
  for (int kt = 0; kt < 16; ++kt) {
    int buf = kt & 1;
    if (kt < 15) STAGE(kt + 1, buf ^ 1);   // issue loads first: overlap w/ compute
    const unsigned short* Ab = &At[buf][0][0];
    const unsigned short* Bb = &Bt[buf][0][0];
    #pragma unroll
    for (int s = 0; s < 2; ++s) {
      int cb = (s*32 + 8*g) ^ rx;          // swizzled column of this frag
      bf16x8 af[4], bfr[4];
      #pragma unroll
      for (int mi = 0; mi < 4; ++mi)
        af[mi] = *(const bf16x8*)(Ab + (wm + mi*16 + lr)*64 + cb);
      #pragma unroll
      for (int nj = 0; nj < 4; ++nj)
        bfr[nj] = *(const bf16x8*)(Bb + (wn + nj*16 + lr)*64 + cb);
      #pragma unroll
      for (int mi = 0; mi < 4; ++mi)
        #pragma unroll
        for (int nj = 0; nj < 4; ++nj)
          acc[mi][nj] = __builtin_amdgcn_mfma_f32_16x16x32_bf16(
              af[mi], bfr[nj], acc[mi][nj], 0, 0, 0);
    }
    __syncthreads();   // drains vmcnt: next buf staged; cur buf free for reuse
  }

  // epilogue: C/D layout col=lane&15, row=(lane>>4)*4+reg  [m89]
  int orow0 = bm*128 + wm;
  int ocol0 = bn*128 + wn;
  const float* bb = basev + (size_t)((bm*128) >> 10)*DM;   // batch uniform per block
  float usv[4], cv[4];
  #pragma unroll
  for (int nj = 0; nj < 4; ++nj) {
    int col = ocol0 + nj*16 + lr;
    usv[nj] = u_s[col];
    cv[nj]  = bb[col] + u_c[col] + mixer_b[col];
  }
  int rbase = g * 4;
  #pragma unroll
  for (int mi = 0; mi < 4; ++mi) {
    #pragma unroll
    for (int r = 0; r < 4; ++r) {
      int row = orow0 + mi*16 + rbase + r;
      float sim = simv[row];
      #pragma unroll
      for (int nj = 0; nj < 4; ++nj) {
        float v = acc[mi][nj][r] + sim*usv[nj] + cv[nj];
        out[(size_t)row*DM + ocol0 + nj*16 + lr] = fmaxf(v, 0.f);
      }
    }
  }
  #undef STAGE
}

extern "C" void kernel_launch(void* const* d_in, const int* in_sizes, int n_in,
                              void* d_out, int out_size, void* d_ws, size_t ws_size,
                              hipStream_t stream) {
  const float* video   = (const float*)d_in[0];
  const float* query   = (const float*)d_in[1];
  const float* vmask   = (const float*)d_in[2];
  const float* qmask   = (const float*)d_in[3];
  const float* sim_w   = (const float*)d_in[4];
  const float* cor_v_w = (const float*)d_in[5];
  const float* cor_q_w = (const float*)d_in[6];
  const float* pool_w  = (const float*)d_in[7];
  const float* mixer_w = (const float*)d_in[8];
  const float* mixer_b = (const float*)d_in[9];
  float* out = (float*)d_out;

  float* fws      = (float*)d_ws;
  float* sentence = fws;                    // 16384
  float* psq      = sentence + 16384;       // 128
  float* u_s      = psq + 128;              // 1024
  float* u_c      = u_s + 1024;             // 1024
  float* basev    = u_c + 1024;             // 16384
  float* simv     = basev + 16384;          // 16384
  float* partial  = simv + 16384;           // 32*18*1024 = 589824
  unsigned short* Ahi = (unsigned short*)(partial + 589824);  // 16M elems (32MB)
  unsigned short* Bhi = Ahi + (size_t)MM*DM;                  // 1M elems (2MB)

  k_sent<<<dim3(16, 8), dim3(256), 0, stream>>>(query, qmask, pool_w,
                                                sentence, psq);
  k_gemvs<<<dim3(32, 8), dim3(256), 0, stream>>>(mixer_w, sentence, sim_w,
                                                 cor_v_w, cor_q_w, partial);
  k_reduce<<<dim3(72), dim3(256), 0, stream>>>(partial, basev, u_s, u_c);
  k_conv<<<dim3(4352), dim3(256), 0, stream>>>(video, sentence, psq, vmask,
                                               mixer_w, Ahi, Bhi, simv);
  k_gemm<<<dim3(1024), dim3(256), 0, stream>>>(Ahi, Bhi, simv, u_s, u_c,
                                               basev, mixer_b, out);
}